// Round 3
// baseline (245.040 us; speedup 1.0000x reference)
//
#include <hip/hip_runtime.h>

// ContourIntegrationLayer: depthwise 3x3 conv (center tap zeroed) + residual.
// x: [32,56,56,256] fp32 NHWC, kernel: [3,3,256] fp32.
//
// R1 finding: kernel is vmem/L1-throughput bound (~19 TB/s data return,
// ~32 B/cyc/CU), NOT HBM bound. R2: 4x thread coarsening along W — each
// wave (64 lanes = 64 float4 channel groups) computes 4 consecutive output
// pixels from an 18-load register window, cutting vmem instrs/output from
// 18 to ~7.75. XCD-chunk swizzle retained (each XCD = 4 whole images).

#define BB 32
#define HH 56
#define WW 56
#define C4 64          // 256 channels / 4 per float4
#define NXCD 8
#define WG 14          // w-groups of 4 per row (56/4)

__global__ __launch_bounds__(256) void contour_kernel(
    const float4* __restrict__ x,     // [B*H*W*C4]
    const float4* __restrict__ kern,  // [9*C4]
    float4* __restrict__ out)         // [B*H*W*C4]
{
    // XCD swizzle: contiguous chunk per XCD (6272 blocks = 8 * 784; 784
    // blocks = exactly 4 images -> zero cross-XCD x sharing).
    const int per_xcd = gridDim.x / NXCD;
    const int blk = (blockIdx.x % NXCD) * per_xcd + blockIdx.x / NXCD;

    const int tid = threadIdx.x;
    const int c4  = tid & 63;
    const int wi  = blk * 4 + (tid >> 6);   // wave index: (b,h,g)
    const int g   = wi % WG;
    const int h   = (wi / WG) % HH;
    const int b   = wi / (WG * HH);
    const int w0  = g * 4;

    // kernel taps (center dead -> compiler eliminates its load)
    float4 kv[3][3];
    #pragma unroll
    for (int r = 0; r < 3; ++r)
        #pragma unroll
        for (int c = 0; c < 3; ++c)
            kv[r][c] = kern[(r * 3 + c) * C4 + c4];

    // register window: rows h-1..h+1, cols w0-1..w0+4 (zeros out of bounds;
    // all predicates wave-uniform)
    const float4 zero = make_float4(0.f, 0.f, 0.f, 0.f);
    float4 win[3][6];
    #pragma unroll
    for (int r = 0; r < 3; ++r) {
        const int hh = h - 1 + r;
        const bool hok = (hh >= 0) && (hh < HH);
        const int rowbase = (b * HH + hh) * WW;
        #pragma unroll
        for (int c = 0; c < 6; ++c) {
            const int ww = w0 - 1 + c;
            const bool ok = hok && (ww >= 0) && (ww < WW);
            win[r][c] = ok ? x[(rowbase + ww) * C4 + c4] : zero;
        }
    }

    const int obase = ((b * HH + h) * WW + w0) * C4 + c4;
    #pragma unroll
    for (int j = 0; j < 4; ++j) {
        float4 acc = win[1][j + 1];   // residual (center pixel)
        #pragma unroll
        for (int r = 0; r < 3; ++r)
            #pragma unroll
            for (int c = 0; c < 3; ++c) {
                if (r == 1 && c == 1) continue;   // masked center tap
                const float4 xv = win[r][j + c];
                const float4 kk = kv[r][c];
                acc.x += xv.x * kk.x;
                acc.y += xv.y * kk.y;
                acc.z += xv.z * kk.z;
                acc.w += xv.w * kk.w;
            }
        out[obase + j * C4] = acc;
    }
}

extern "C" void kernel_launch(void* const* d_in, const int* in_sizes, int n_in,
                              void* d_out, int out_size, void* d_ws, size_t ws_size,
                              hipStream_t stream) {
    const float4* x    = (const float4*)d_in[0];
    const float4* kern = (const float4*)d_in[1];
    float4* out        = (float4*)d_out;

    const int waves = BB * HH * WG;          // 25088 waves
    const int block = 256;                    // 4 waves/block
    const int grid  = waves / 4;              // 6272 blocks (8 * 784)
    contour_kernel<<<grid, block, 0, stream>>>(x, kern, out);
}

// Round 4
// 221.073 us; speedup vs baseline: 1.1084x; 1.1084x over previous
//
#include <hip/hip_runtime.h>

// ContourIntegrationLayer: depthwise 3x3 conv (center tap zeroed) + residual.
// x: [32,56,56,256] fp32 NHWC, kernel: [3,3,256] fp32.
//
// R1 finding: L1/vmem-return bound (~32 B/cyc/CU). R2 finding: default
// launch_bounds caps VGPRs at ~56 -> register window serialized, latency
// bound. R3: (a) kernel taps staged in LDS (off the vmem pipe), (b) 4x
// H-coarsening — thread computes 4 vertically-adjacent outputs from a
// streamed 6x3 window: 5.5 vmem instr/output vs R1's 18, (c)
// __launch_bounds__(256,4) -> 128 VGPR budget, 16 waves/CU.

#define BB 32
#define HH 56
#define WW 56
#define C4 64          // 256 channels / 4 per float4
#define NXCD 8
#define TH 4           // outputs per thread along H
#define HG (HH / TH)   // 14 h-groups

__global__ __launch_bounds__(256, 4) void contour_kernel(
    const float4* __restrict__ x,     // [B*H*W*C4]
    const float4* __restrict__ kern,  // [9*C4]
    float4* __restrict__ out)         // [B*H*W*C4]
{
    // Stage the 9 KB kernel table in LDS once per block.
    __shared__ float4 klds[9 * C4];
    for (int i = threadIdx.x; i < 9 * C4; i += 256) klds[i] = kern[i];
    __syncthreads();

    // XCD swizzle: contiguous chunk per XCD (6272 = 8 * 784 blocks; 784
    // blocks = 4 whole images -> zero cross-XCD x sharing).
    const int per_xcd = gridDim.x / NXCD;
    const int blk = (blockIdx.x % NXCD) * per_xcd + blockIdx.x / NXCD;

    const int tid = threadIdx.x;
    const int c4  = tid & 63;
    const int wi  = blk * 4 + (tid >> 6);   // wave index over (b, hg, w)
    const int w   = wi % WW;                 // wave-uniform
    const int hg  = (wi / WW) % HG;          // wave-uniform
    const int b   = wi / (WW * HG);
    const int h0  = hg * TH;

    // kernel taps from LDS (center tap unused -> dead)
    float4 kv[3][3];
    #pragma unroll
    for (int r = 0; r < 3; ++r)
        #pragma unroll
        for (int c = 0; c < 3; ++c)
            if (!(r == 1 && c == 1)) kv[r][c] = klds[(r * 3 + c) * C4 + c4];

    const float4 zero = make_float4(0.f, 0.f, 0.f, 0.f);
    const bool wl = (w > 0), wr = (w < WW - 1);

    float4 acc[TH];
    #pragma unroll
    for (int j = 0; j < TH; ++j) acc[j] = zero;

    // Stream 6 window rows h0-1 .. h0+4. Window row r contributes to output
    // oh with compile-time kern row kr = r - oh (valid 0..2).
    #pragma unroll
    for (int r = 0; r < TH + 2; ++r) {
        const int hr = h0 - 1 + r;
        if (hr < 0 || hr >= HH) continue;    // wave-uniform scalar branch
        const int rb = (b * HH + hr) * WW + w;
        const float4 xm = wl ? x[(rb - 1) * C4 + c4] : zero;
        const float4 xc = x[rb * C4 + c4];
        const float4 xp = wr ? x[(rb + 1) * C4 + c4] : zero;

        #pragma unroll
        for (int oh = 0; oh < TH; ++oh) {
            const int kr = r - oh;           // compile-time
            if (kr < 0 || kr > 2) continue;
            float4& a = acc[oh];
            // left + right cols always active taps
            a.x += xm.x * kv[kr][0].x;  a.y += xm.y * kv[kr][0].y;
            a.z += xm.z * kv[kr][0].z;  a.w += xm.w * kv[kr][0].w;
            a.x += xp.x * kv[kr][2].x;  a.y += xp.y * kv[kr][2].y;
            a.z += xp.z * kv[kr][2].z;  a.w += xp.w * kv[kr][2].w;
            if (kr == 1) {
                // center column, center row: masked tap, add residual instead
                a.x += xc.x;  a.y += xc.y;  a.z += xc.z;  a.w += xc.w;
            } else {
                a.x += xc.x * kv[kr][1].x;  a.y += xc.y * kv[kr][1].y;
                a.z += xc.z * kv[kr][1].z;  a.w += xc.w * kv[kr][1].w;
            }
        }
    }

    const int obase = ((b * HH + h0) * WW + w) * C4 + c4;
    #pragma unroll
    for (int oh = 0; oh < TH; ++oh)
        out[obase + oh * WW * C4] = acc[oh];
}

extern "C" void kernel_launch(void* const* d_in, const int* in_sizes, int n_in,
                              void* d_out, int out_size, void* d_ws, size_t ws_size,
                              hipStream_t stream) {
    const float4* x    = (const float4*)d_in[0];
    const float4* kern = (const float4*)d_in[1];
    float4* out        = (float4*)d_out;

    const int waves = BB * HG * WW;           // 25088 waves (b, hg, w)
    const int block = 256;                    // 4 waves/block
    const int grid  = waves / 4;              // 6272 blocks (8 * 784)
    contour_kernel<<<grid, block, 0, stream>>>(x, kern, out);
}